// Round 11
// baseline (335.437 us; speedup 1.0000x reference)
//
#include <hip/hip_runtime.h>

#define BATCH 1024
#define SEQ   144
#define DIM   192
#define NH    6
#define HD    32
#define SCALE 0.17677669529663687f   // 1/sqrt(32)

typedef __bf16 bf16x8 __attribute__((ext_vector_type(8)));
typedef __bf16 bf16x4 __attribute__((ext_vector_type(4)));
typedef float  f32x4  __attribute__((ext_vector_type(4)));

// LDS-only barrier (proven R9): orders ds_write->ds_read without draining vmcnt.
__device__ __forceinline__ void lds_barrier() {
    __builtin_amdgcn_sched_barrier(0);
    asm volatile("s_waitcnt lgkmcnt(0)" ::: "memory");
    __builtin_amdgcn_s_barrier();
    __builtin_amdgcn_sched_barrier(0);
}

// ---- workspace layout (bytes) ----
#define WS_W1T   0          // bf16 [576][192]  w1t[c][k] = w1[k][c] (*SCALE for c<192)
#define WS_W2T   221184     // bf16 [192][192]  w2t[n][k] = w2[k][n]
#define WS_B1S   294912     // f32  [576]       b1 (*SCALE for c<192)
#define WS_BM    297216     // bf16 [6][144][144]  bm[h][query][key] = bias + mask
#define WS_OPRE  546048     // bf16 [1024][144][192] pre-projection attention output

// ---------------------------------------------------------------------------
__global__ __launch_bounds__(256) void k_prep(
        const float* __restrict__ w1, const float* __restrict__ w2,
        const float* __restrict__ b1, const float* __restrict__ bt,
        const int* __restrict__ pidx, const int* __restrict__ mask,
        char* __restrict__ ws) {
    __bf16* w1t = (__bf16*)(ws + WS_W1T);
    __bf16* w2t = (__bf16*)(ws + WS_W2T);
    float*  b1s = (float*)(ws + WS_B1S);
    __bf16* bm  = (__bf16*)(ws + WS_BM);
    const int blk = blockIdx.x, t = threadIdx.x;
    if (blk < 432) {
        int idx = blk * 256 + t;
        int k = idx / 576, c = idx % 576;
        float v = w1[idx] * (c < 192 ? SCALE : 1.0f);
        w1t[c * 192 + k] = (__bf16)v;
    } else if (blk < 576) {
        int idx = (blk - 432) * 256 + t;
        int k = idx / 192, n = idx % 192;
        w2t[n * 192 + k] = (__bf16)w2[idx];
    } else if (blk < 657) {
        int idx = (blk - 576) * 256 + t;   // idx = query*144 + key
        int p = pidx[idx];
        float add = (mask[idx] == 0) ? -1e9f : 0.0f;
#pragma unroll
        for (int h = 0; h < NH; ++h)
            bm[h * 20736 + idx] = (__bf16)(bt[p * NH + h] + add);
    } else {
        for (int c = t; c < 576; c += 256)
            b1s[c] = b1[c] * (c < 192 ? SCALE : 1.0f);
    }
}

// ---------------------------------------------------------------------------
// Fused QKV + attention. Block = (h, 8 b's), processed as 4 PAIRS: the two
// batches' P1/P2/P3 chains are independent and jointly interleaved -> ~2x ILP
// per wave at unchanged occupancy/barrier rate. All machinery = proven R9
// code duplicated A/B. Ws frag-linear; LDS 102400 B; 2 lds_barriers per pair.
// ---------------------------------------------------------------------------
__global__ __launch_bounds__(576, 3) void k_attn(
        const float* __restrict__ x, char* __restrict__ ws) {
    const __bf16* w1t = (const __bf16*)(ws + WS_W1T);
    const float*  b1s = (const float*)(ws + WS_B1S);
    const __bf16* bmB = (const __bf16*)(ws + WS_BM);
    __bf16* opre = (__bf16*)(ws + WS_OPRE);

    __shared__ char smem[102400];
    __bf16* Ws  = (__bf16*)(smem);            // [36 frags][64][8]  36864B
    __bf16* KsA = (__bf16*)(smem + 36864);    // [144][40]
    __bf16* KsB = (__bf16*)(smem + 48384);
    __bf16* VtA = (__bf16*)(smem + 59904);    // [32][152]
    __bf16* VtB = (__bf16*)(smem + 69632);
    __bf16* QsA = (__bf16*)(smem + 79360);    // [144][40] wave-private (Q/Pw/O)
    __bf16* QsB = (__bf16*)(smem + 90880);

    const int g  = blockIdx.x;                // 768 = 8 XCD x 96
    const int h  = (g >> 3) % 6;
    const int bg = (g & 7) + 8 * ((g >> 3) / 6);
    const int b0 = bg * 8;

    const int tid  = threadIdx.x;
    const int w    = tid >> 6;
    const int lane = tid & 63;
    const int lr   = lane & 15;
    const int lg   = lane >> 4;
    const int m0   = w * 16;
    const f32x4 zf = {0.f, 0.f, 0.f, 0.f};
    const bf16x8 zb = {(__bf16)0.f,(__bf16)0.f,(__bf16)0.f,(__bf16)0.f,
                       (__bf16)0.f,(__bf16)0.f,(__bf16)0.f,(__bf16)0.f};

    // ---- stage Ws fragment-linear (chunk c -> frag c>>6, lane c&63)
#pragma unroll
    for (int it = 0; it < 4; ++it) {
        int c = tid + it * 576;
        int f = c >> 6, ln = c & 63;
        int n = f / 6, kk = f - n * 6;
        int flr = ln & 15, flg = ln >> 4;
        *(bf16x8*)&Ws[c * 8] = *(const bf16x8*)(w1t +
            (((n >> 1) * 192 + h * 32 + (n & 1) * 16 + flr) * 192 + kk * 32 + flg * 8));
    }

    // ---- hoisted attn-bias fragments (b-invariant, shared by both pair halves)
    bf16x4 bb[9];
    {
        const __bf16* bmh = bmB + h * 20736 + (m0 + lr) * SEQ;
#pragma unroll
        for (int i = 0; i < 9; ++i) bb[i] = *(const bf16x4*)&bmh[i * 16 + lg * 4];
    }

    lds_barrier();   // Ws visible

    // X strip fetch+convert (R9-proven)
    auto xfetch = [&](int bidx, bf16x8 (&aX)[6]) {
        const float* xr = x + ((size_t)bidx * SEQ + m0 + lr) * DIM + lg * 8;
#pragma unroll
        for (int kk = 0; kk < 6; ++kk) {
            f32x4 u = *(const f32x4*)(xr + kk * 32);
            f32x4 v = *(const f32x4*)(xr + kk * 32 + 4);
            bf16x8 t;
            t[0]=(__bf16)u[0]; t[1]=(__bf16)u[1]; t[2]=(__bf16)u[2]; t[3]=(__bf16)u[3];
            t[4]=(__bf16)v[0]; t[5]=(__bf16)v[1]; t[6]=(__bf16)v[2]; t[7]=(__bf16)v[3];
            aX[kk] = t;
        }
    };

    // P1: QKV projection (R9-proven body)
    auto P1 = [&](const bf16x8 (&aX)[6], __bf16* KS, __bf16* VT, __bf16* QS) {
        f32x4 acc[6];
#pragma unroll
        for (int n = 0; n < 6; ++n) acc[n] = zf;
#pragma unroll
        for (int kk = 0; kk < 6; ++kk)
#pragma unroll
            for (int n = 0; n < 6; ++n) {
                bf16x8 bF = *(bf16x8*)&Ws[((n * 6 + kk) * 64 + lane) * 8];
                acc[n] = __builtin_amdgcn_mfma_f32_16x16x32_bf16(aX[kk], bF, acc[n], 0, 0, 0);
            }
#pragma unroll
        for (int n = 0; n < 6; ++n) {
            int j = (n & 1) * 16 + lr;
            float bv = b1s[(n >> 1) * 192 + h * 32 + j];
            if (n < 2) {
#pragma unroll
                for (int r = 0; r < 4; ++r)
                    QS[(m0 + lg * 4 + r) * 40 + j] = (__bf16)(acc[n][r] + bv);
            } else if (n < 4) {
#pragma unroll
                for (int r = 0; r < 4; ++r)
                    KS[(m0 + lg * 4 + r) * 40 + j] = (__bf16)(acc[n][r] + bv);
            } else {
                bf16x4 pk;
#pragma unroll
                for (int r = 0; r < 4; ++r) pk[r] = (__bf16)(acc[n][r] + bv);
                *(bf16x4*)&VT[j * 152 + m0 + lg * 4] = pk;   // [dim][key]
            }
        }
    };

#pragma unroll 1
    for (int pr = 0; pr < 4; ++pr) {
        const int bA = b0 + 2 * pr, bB = bA + 1;

        // ---- X for both halves (loads ride across barrier A; one bubble/pair)
        bf16x8 aXA[6], aXB[6];
        xfetch(bA, aXA);
        xfetch(bB, aXB);

        lds_barrier();   // barrier A: previous pair's Ks/Vt reads complete

        P1(aXA, KsA, VtA, QsA);
        P1(aXB, KsB, VtB, QsB);

        lds_barrier();   // barrier B: Ks/Vt published

        bf16x8 qfA = *(bf16x8*)&QsA[(m0 + lr) * 40 + lg * 8];
        bf16x8 qfB = *(bf16x8*)&QsB[(m0 + lr) * 40 + lg * 8];

        // ---- P2 joint: S^T frags + bias + softmax, A/B interleaved
        f32x4 stA[9], stB[9];
#pragma unroll
        for (int i = 0; i < 9; ++i) {
            bf16x8 aFA = *(bf16x8*)&KsA[(i * 16 + lr) * 40 + lg * 8];
            bf16x8 aFB = *(bf16x8*)&KsB[(i * 16 + lr) * 40 + lg * 8];
            stA[i] = __builtin_amdgcn_mfma_f32_16x16x32_bf16(aFA, qfA, zf, 0, 0, 0);
            stB[i] = __builtin_amdgcn_mfma_f32_16x16x32_bf16(aFB, qfB, zf, 0, 0, 0);
        }
        float mxA = -3.0e38f, mxB = -3.0e38f;
#pragma unroll
        for (int i = 0; i < 9; ++i)
#pragma unroll
            for (int r = 0; r < 4; ++r) {
                stA[i][r] += (float)bb[i][r];  mxA = fmaxf(mxA, stA[i][r]);
                stB[i][r] += (float)bb[i][r];  mxB = fmaxf(mxB, stB[i][r]);
            }
        mxA = fmaxf(mxA, __shfl_xor(mxA, 16));  mxB = fmaxf(mxB, __shfl_xor(mxB, 16));
        mxA = fmaxf(mxA, __shfl_xor(mxA, 32));  mxB = fmaxf(mxB, __shfl_xor(mxB, 32));
        float sA = 0.f, sB = 0.f;
#pragma unroll
        for (int i = 0; i < 9; ++i)
#pragma unroll
            for (int r = 0; r < 4; ++r) {
                float eA = __expf(stA[i][r] - mxA);  stA[i][r] = eA;  sA += eA;
                float eB = __expf(stB[i][r] - mxB);  stB[i][r] = eB;  sB += eB;
            }
        sA += __shfl_xor(sA, 16);  sB += __shfl_xor(sB, 16);
        sA += __shfl_xor(sA, 32);  sB += __shfl_xor(sB, 32);
        float invA = 1.f / sA, invB = 1.f / sB;
#pragma unroll
        for (int i = 0; i < 9; ++i)
#pragma unroll
            for (int r = 0; r < 4; ++r) {
                stA[i][r] *= invA;
                stB[i][r] *= invB;
            }

        // ---- P3 joint: PV via per-wave P scratch (overlaid on Qs strips)
        __bf16* PwA = QsA + m0 * 40;
        __bf16* PwB = QsB + m0 * 40;
        f32x4 oA0 = zf, oA1 = zf, oB0 = zf, oB1 = zf;
#pragma unroll
        for (int s = 0; s < 4; ++s) {
#pragma unroll
            for (int d = 0; d < 2; ++d) {
                int ii = 2 * s + d;
                bf16x4 pkA, pkB;
#pragma unroll
                for (int r = 0; r < 4; ++r) { pkA[r] = (__bf16)stA[ii][r];
                                              pkB[r] = (__bf16)stB[ii][r]; }
                *(bf16x4*)&PwA[lr * 40 + d * 16 + lg * 4] = pkA;
                *(bf16x4*)&PwB[lr * 40 + d * 16 + lg * 4] = pkB;
            }
            bf16x8 aPA = *(bf16x8*)&PwA[lr * 40 + lg * 8];
            bf16x8 aPB = *(bf16x8*)&PwB[lr * 40 + lg * 8];
            bf16x8 vA0 = *(bf16x8*)&VtA[lr * 152 + s * 32 + lg * 8];
            bf16x8 vA1 = *(bf16x8*)&VtA[(16 + lr) * 152 + s * 32 + lg * 8];
            bf16x8 vB0 = *(bf16x8*)&VtB[lr * 152 + s * 32 + lg * 8];
            bf16x8 vB1 = *(bf16x8*)&VtB[(16 + lr) * 152 + s * 32 + lg * 8];
            oA0 = __builtin_amdgcn_mfma_f32_16x16x32_bf16(aPA, vA0, oA0, 0, 0, 0);
            oA1 = __builtin_amdgcn_mfma_f32_16x16x32_bf16(aPA, vA1, oA1, 0, 0, 0);
            oB0 = __builtin_amdgcn_mfma_f32_16x16x32_bf16(aPB, vB0, oB0, 0, 0, 0);
            oB1 = __builtin_amdgcn_mfma_f32_16x16x32_bf16(aPB, vB1, oB1, 0, 0, 0);
        }
        {   // tail keys 128..143: lanes lg>=2 supply zeros
            bf16x4 pkA, pkB;
#pragma unroll
            for (int r = 0; r < 4; ++r) { pkA[r] = (__bf16)stA[8][r];
                                          pkB[r] = (__bf16)stB[8][r]; }
            *(bf16x4*)&PwA[lr * 40 + lg * 4] = pkA;
            *(bf16x4*)&PwB[lr * 40 + lg * 4] = pkB;
            bf16x8 aPA = zb, vA0 = zb, vA1 = zb, aPB = zb, vB0 = zb, vB1 = zb;
            if (lg < 2) {
                aPA = *(bf16x8*)&PwA[lr * 40 + lg * 8];
                vA0 = *(bf16x8*)&VtA[lr * 152 + 128 + lg * 8];
                vA1 = *(bf16x8*)&VtA[(16 + lr) * 152 + 128 + lg * 8];
                aPB = *(bf16x8*)&PwB[lr * 40 + lg * 8];
                vB0 = *(bf16x8*)&VtB[lr * 152 + 128 + lg * 8];
                vB1 = *(bf16x8*)&VtB[(16 + lr) * 152 + 128 + lg * 8];
            }
            oA0 = __builtin_amdgcn_mfma_f32_16x16x32_bf16(aPA, vA0, oA0, 0, 0, 0);
            oA1 = __builtin_amdgcn_mfma_f32_16x16x32_bf16(aPA, vA1, oA1, 0, 0, 0);
            oB0 = __builtin_amdgcn_mfma_f32_16x16x32_bf16(aPB, vB0, oB0, 0, 0, 0);
            oB1 = __builtin_amdgcn_mfma_f32_16x16x32_bf16(aPB, vB1, oB1, 0, 0, 0);
        }

        // ---- O restage (coalesce) + stores for both halves
#pragma unroll
        for (int r = 0; r < 4; ++r) {
            PwA[(lg * 4 + r) * 40 + lr]      = (__bf16)oA0[r];
            PwA[(lg * 4 + r) * 40 + 16 + lr] = (__bf16)oA1[r];
            PwB[(lg * 4 + r) * 40 + lr]      = (__bf16)oB0[r];
            PwB[(lg * 4 + r) * 40 + 16 + lr] = (__bf16)oB1[r];
        }
        {
            int row = lane >> 2, c = lane & 3;
            bf16x8 ovA = *(bf16x8*)&PwA[row * 40 + c * 8];
            bf16x8 ovB = *(bf16x8*)&PwB[row * 40 + c * 8];
            *(bf16x8*)&opre[((size_t)bA * SEQ + m0 + row) * DIM + h * HD + c * 8] = ovA;
            *(bf16x8*)&opre[((size_t)bB * SEQ + m0 + row) * DIM + h * HD + c * 8] = ovB;
        }
    }
}

// ---------------------------------------------------------------------------
// Out-projection (proven): W2 in registers, M-loop, dbuf A-staging,
// LDS-only barriers.
// ---------------------------------------------------------------------------
__global__ __launch_bounds__(256, 3) void k_proj(
        const char* __restrict__ ws, const float* __restrict__ b2,
        float* __restrict__ out) {
    const __bf16* opre = (const __bf16*)(ws + WS_OPRE);
    const __bf16* w2t  = (const __bf16*)(ws + WS_W2T);
    __shared__ __bf16 As[2][16 * 200];

    const int tid = threadIdx.x;
    const int w = tid >> 6, lr = tid & 15, lg = (tid & 63) >> 4;
    const f32x4 zf = {0.f, 0.f, 0.f, 0.f};

    bf16x8 bW[3][6];
    float bcol[3];
#pragma unroll
    for (int i = 0; i < 3; ++i) {
        int col = (w * 3 + i) * 16 + lr;
        bcol[i] = b2[col];
#pragma unroll
        for (int kk = 0; kk < 6; ++kk)
            bW[i][kk] = *(const bf16x8*)(w2t + (col * 192 + kk * 32 + lg * 8));
    }

    const int i0r = tid / 24,  i0c = tid % 24;
    const int i1r = (tid + 256) / 24, i1c = (tid + 256) % 24;
    const bool has1 = tid < 128;

    {
        size_t row0 = (size_t)blockIdx.x * 9 * 16;
        bf16x8 s0 = *(const bf16x8*)&opre[(row0 + i0r) * DIM + i0c * 8];
        *(bf16x8*)&As[0][i0r * 200 + i0c * 8] = s0;
        if (has1) {
            bf16x8 s1 = *(const bf16x8*)&opre[(row0 + i1r) * DIM + i1c * 8];
            *(bf16x8*)&As[0][i1r * 200 + i1c * 8] = s1;
        }
    }

    for (int t = 0; t < 9; ++t) {
        bf16x8 n0, n1;
        if (t < 8) {
            size_t rown = ((size_t)blockIdx.x * 9 + t + 1) * 16;
            n0 = *(const bf16x8*)&opre[(rown + i0r) * DIM + i0c * 8];
            if (has1) n1 = *(const bf16x8*)&opre[(rown + i1r) * DIM + i1c * 8];
        }
        lds_barrier();
        const __bf16* A = As[t & 1];
        f32x4 acc[3];
#pragma unroll
        for (int i = 0; i < 3; ++i) acc[i] = zf;
#pragma unroll
        for (int kk = 0; kk < 6; ++kk) {
            bf16x8 aF = *(const bf16x8*)&A[lr * 200 + kk * 32 + lg * 8];
#pragma unroll
            for (int i = 0; i < 3; ++i)
                acc[i] = __builtin_amdgcn_mfma_f32_16x16x32_bf16(aF, bW[i][kk], acc[i], 0, 0, 0);
        }
        size_t row0 = ((size_t)blockIdx.x * 9 + t) * 16;
#pragma unroll
        for (int i = 0; i < 3; ++i) {
            int col = (w * 3 + i) * 16 + lr;
#pragma unroll
            for (int r = 0; r < 4; ++r)
                out[(row0 + lg * 4 + r) * DIM + col] = acc[i][r] + bcol[i];
        }
        if (t < 8) {
            *(bf16x8*)&As[(t + 1) & 1][i0r * 200 + i0c * 8] = n0;
            if (has1) *(bf16x8*)&As[(t + 1) & 1][i1r * 200 + i1c * 8] = n1;
        }
    }
}

// ---------------------------------------------------------------------------
extern "C" void kernel_launch(void* const* d_in, const int* in_sizes, int n_in,
                              void* d_out, int out_size, void* d_ws, size_t ws_size,
                              hipStream_t stream) {
    const float* x    = (const float*)d_in[0];
    const float* w1   = (const float*)d_in[1];
    const float* b1   = (const float*)d_in[2];
    const float* w2   = (const float*)d_in[3];
    const float* b2   = (const float*)d_in[4];
    const float* bt   = (const float*)d_in[5];
    const int*   pidx = (const int*)d_in[6];
    const int*   mask = (const int*)d_in[7];
    float* out = (float*)d_out;
    char*  ws  = (char*)d_ws;

    k_prep<<<658, 256, 0, stream>>>(w1, w2, b1, bt, pidx, mask, ws);
    k_attn<<<768, 576, 0, stream>>>(x, ws);
    k_proj<<<1024, 256, 0, stream>>>(ws, b2, out);
}

// Round 12
// 213.003 us; speedup vs baseline: 1.5748x; 1.5748x over previous
//
#include <hip/hip_runtime.h>

#define BATCH 1024
#define SEQ   144
#define DIM   192
#define NH    6
#define HD    32
#define SCALE 0.17677669529663687f   // 1/sqrt(32)

typedef __bf16 bf16x8 __attribute__((ext_vector_type(8)));
typedef __bf16 bf16x4 __attribute__((ext_vector_type(4)));
typedef float  f32x4  __attribute__((ext_vector_type(4)));

// LDS-only barrier (proven R9): orders ds_write->ds_read without draining vmcnt.
__device__ __forceinline__ void lds_barrier() {
    __builtin_amdgcn_sched_barrier(0);
    asm volatile("s_waitcnt lgkmcnt(0)" ::: "memory");
    __builtin_amdgcn_s_barrier();
    __builtin_amdgcn_sched_barrier(0);
}

// ---- workspace layout (bytes) ----
#define WS_W1T   0          // bf16 [576][192]  w1t[c][k] = w1[k][c] (*SCALE for c<192)
#define WS_W2T   221184     // bf16 [192][192]  w2t[n][k] = w2[k][n]
#define WS_B1S   294912     // f32  [576]       b1 (*SCALE for c<192)
#define WS_BM    297216     // bf16 [6][144][144]  bm[h][query][key] = bias + mask
#define WS_QF    546048     // bf16 [1024*6][144][32]  q ; aliased as opre after read
#define WS_KF    57169152   // bf16 [1024*6][144][32]  k
#define WS_VT    113792256  // bf16 [1024*6][32][144]  v^T
// total need 170415360 B (confirmed available in round 6)

#define BH_STRIDE 4608      // 144*32 elems per (b,h)

// ---------------------------------------------------------------------------
__global__ __launch_bounds__(256) void k_prep(
        const float* __restrict__ w1, const float* __restrict__ w2,
        const float* __restrict__ b1, const float* __restrict__ bt,
        const int* __restrict__ pidx, const int* __restrict__ mask,
        char* __restrict__ ws) {
    __bf16* w1t = (__bf16*)(ws + WS_W1T);
    __bf16* w2t = (__bf16*)(ws + WS_W2T);
    float*  b1s = (float*)(ws + WS_B1S);
    __bf16* bm  = (__bf16*)(ws + WS_BM);
    const int blk = blockIdx.x, t = threadIdx.x;
    if (blk < 432) {
        int idx = blk * 256 + t;
        int k = idx / 576, c = idx % 576;
        float v = w1[idx] * (c < 192 ? SCALE : 1.0f);
        w1t[c * 192 + k] = (__bf16)v;
    } else if (blk < 576) {
        int idx = (blk - 432) * 256 + t;
        int k = idx / 192, n = idx % 192;
        w2t[n * 192 + k] = (__bf16)w2[idx];
    } else if (blk < 657) {
        int idx = (blk - 576) * 256 + t;   // idx = query*144 + key
        int p = pidx[idx];
        float add = (mask[idx] == 0) ? -1e9f : 0.0f;
#pragma unroll
        for (int h = 0; h < NH; ++h)
            bm[h * 20736 + idx] = (__bf16)(bt[p * NH + h] + add);
    } else {
        for (int c = t; c < 576; c += 256)
            b1s[c] = b1[c] * (c < 192 ? SCALE : 1.0f);
    }
}

// ---------------------------------------------------------------------------
// QKV GEMM in the PROVEN register-B pattern (R7 k_proj: ~1.2 PF measured).
// Grid (1024, 3): block = (batch b, col-group cg in {q,k,v}); 4 waves;
// wave holds its 48-col W1 slice in 18 persistent B-frags (72 VGPR).
// 9 M-tiles of 16 rows, double-buffered LDS A-staging (fp32 -> bf16 inline).
// Epilogue scatters to qf / kf / v^T with +bias.
// ---------------------------------------------------------------------------
__global__ __launch_bounds__(256, 3) void k_qkv(
        const float* __restrict__ x, char* __restrict__ ws) {
    const __bf16* w1t = (const __bf16*)(ws + WS_W1T);
    const float*  b1s = (const float*)(ws + WS_B1S);
    __bf16* qf  = (__bf16*)(ws + WS_QF);
    __bf16* kf  = (__bf16*)(ws + WS_KF);
    __bf16* vtf = (__bf16*)(ws + WS_VT);

    __shared__ __bf16 As[2][16 * 200];
    const int tid = threadIdx.x;
    const int w = tid >> 6, lr = tid & 15, lg = (tid & 63) >> 4;
    const int b  = blockIdx.x;
    const int cg = blockIdx.y;              // 0=q, 1=k, 2=v
    const f32x4 zf = {0.f, 0.f, 0.f, 0.f};

    // persistent B-frags + bias for this wave's 48 cols of this group
    bf16x8 bW[3][6];
    float bcol[3];
#pragma unroll
    for (int i = 0; i < 3; ++i) {
        int col = cg * 192 + (w * 3 + i) * 16 + lr;
        bcol[i] = b1s[col];
#pragma unroll
        for (int kk = 0; kk < 6; ++kk)
            bW[i][kk] = *(const bf16x8*)(w1t + (col * 192 + kk * 32 + lg * 8));
    }

    // A staging: 16 rows x 192 cols fp32 = 768 f32x4 chunks, 3 per thread
    const int c0 = tid, c1 = tid + 256, c2 = tid + 512;
    auto stage = [&](int t, int buf) {
        const float* src = x + ((size_t)b * SEQ + t * 16) * DIM;
#pragma unroll
        for (int j = 0; j < 3; ++j) {
            int c = c0 + j * 256;
            int row = c / 48, c4 = (c % 48) * 4;
            f32x4 v = *(const f32x4*)&src[row * DIM + c4];
            bf16x4 pk;
            pk[0] = (__bf16)v[0]; pk[1] = (__bf16)v[1];
            pk[2] = (__bf16)v[2]; pk[3] = (__bf16)v[3];
            *(bf16x4*)&As[buf][row * 200 + c4] = pk;
        }
    };
    (void)c1; (void)c2;

    stage(0, 0);

    for (int t = 0; t < 9; ++t) {
        // prefetch next tile into regs
        f32x4 nxt[3];
        if (t < 8) {
            const float* src = x + ((size_t)b * SEQ + (t + 1) * 16) * DIM;
#pragma unroll
            for (int j = 0; j < 3; ++j) {
                int c = c0 + j * 256;
                int row = c / 48, c4 = (c % 48) * 4;
                nxt[j] = *(const f32x4*)&src[row * DIM + c4];
            }
        }
        lds_barrier();
        const __bf16* A = As[t & 1];
        f32x4 acc[3];
#pragma unroll
        for (int i = 0; i < 3; ++i) acc[i] = zf;
#pragma unroll
        for (int kk = 0; kk < 6; ++kk) {
            bf16x8 aF = *(const bf16x8*)&A[lr * 200 + kk * 32 + lg * 8];
#pragma unroll
            for (int i = 0; i < 3; ++i)
                acc[i] = __builtin_amdgcn_mfma_f32_16x16x32_bf16(aF, bW[i][kk], acc[i], 0, 0, 0);
        }
        // epilogue: +bias, scatter
        const int m = t * 16 + lg * 4;       // +r
#pragma unroll
        for (int i = 0; i < 3; ++i) {
            int j2 = (w * 3 + i) * 16 + lr;  // 0..191 within group
            int h = j2 >> 5, j = j2 & 31;
            size_t bh = (size_t)(b * NH + h);
            if (cg == 0) {
                __bf16* d = qf + bh * BH_STRIDE + (size_t)m * HD + j;
#pragma unroll
                for (int r = 0; r < 4; ++r) d[r * HD] = (__bf16)(acc[i][r] + bcol[i]);
            } else if (cg == 1) {
                __bf16* d = kf + bh * BH_STRIDE + (size_t)m * HD + j;
#pragma unroll
                for (int r = 0; r < 4; ++r) d[r * HD] = (__bf16)(acc[i][r] + bcol[i]);
            } else {
                bf16x4 pk;
#pragma unroll
                for (int r = 0; r < 4; ++r) pk[r] = (__bf16)(acc[i][r] + bcol[i]);
                *(bf16x4*)&vtf[bh * BH_STRIDE + (size_t)j * SEQ + m] = pk;
            }
        }
        if (t < 8) {
#pragma unroll
            for (int j = 0; j < 3; ++j) {
                int c = c0 + j * 256;
                int row = c / 48, c4 = (c % 48) * 4;
                f32x4 v = nxt[j];
                bf16x4 pk;
                pk[0] = (__bf16)v[0]; pk[1] = (__bf16)v[1];
                pk[2] = (__bf16)v[2]; pk[3] = (__bf16)v[3];
                *(bf16x4*)&As[(t + 1) & 1][row * 200 + c4] = pk;
            }
        }
    }
}

// ---------------------------------------------------------------------------
// Attention-only per (b,h): K,V cooperatively staged (one contiguous 16B
// load + one ds_write per thread), Q per-lane direct (coalesced), bias L2.
// ONE barrier; then R9-proven P2/softmax/P3. LDS exactly 32768 B -> 2
// blocks/CU. opre aliases qf (each block overwrites only the slice it read).
// ---------------------------------------------------------------------------
__global__ __launch_bounds__(576, 2) void k_attn3(char* __restrict__ ws) {
    const __bf16* bmB = (const __bf16*)(ws + WS_BM);
    const __bf16* qf  = (const __bf16*)(ws + WS_QF);
    const __bf16* kf  = (const __bf16*)(ws + WS_KF);
    const __bf16* vtf = (const __bf16*)(ws + WS_VT);
    __bf16* opre = (__bf16*)(ws + WS_QF);   // alias: own slice, read-then-write

    __shared__ char smem[32768];
    __bf16* Ks  = (__bf16*)smem;             // [144][40]  11520 B
    __bf16* Vt  = (__bf16*)(smem + 11520);   // [32][152]   9728 B
    __bf16* Pws = (__bf16*)(smem + 21248);   // 9 x [16][40] wave-private

    const int bx = blockIdx.x;               // 6144 = 6 h-groups x 1024 b
    const int h  = bx >> 10;
    const int b  = bx & 1023;
    const size_t bh = (size_t)(b * NH + h);

    const int tid  = threadIdx.x;
    const int w    = tid >> 6;
    const int lane = tid & 63;
    const int lr   = lane & 15;
    const int lg   = lane >> 4;
    const int m0   = w * 16;
    const f32x4 zf = {0.f, 0.f, 0.f, 0.f};
    const bf16x8 zb = {(__bf16)0.f,(__bf16)0.f,(__bf16)0.f,(__bf16)0.f,
                       (__bf16)0.f,(__bf16)0.f,(__bf16)0.f,(__bf16)0.f};

    // ---- issue all global loads up front
    bf16x8 kch = *(const bf16x8*)(kf  + bh * BH_STRIDE + (size_t)tid * 8);
    bf16x8 vch = *(const bf16x8*)(vtf + bh * BH_STRIDE + (size_t)tid * 8);
    bf16x8 qF  = *(const bf16x8*)(qf  + bh * BH_STRIDE + (size_t)(m0 + lr) * HD + lg * 8);
    bf16x4 bb[9];
    {
        const __bf16* bmh = bmB + h * 20736 + (m0 + lr) * SEQ;
#pragma unroll
        for (int i = 0; i < 9; ++i) bb[i] = *(const bf16x4*)&bmh[i * 16 + lg * 4];
    }

    // ---- stage to LDS (chunk id == linear addr: row=tid>>2/part for K)
    *(bf16x8*)&Ks[(tid >> 2) * 40 + (tid & 3) * 8] = kch;
    {
        int vr = tid / 18, vc = tid % 18;
        *(bf16x8*)&Vt[vr * 152 + vc * 8] = vch;
    }
    lds_barrier();   // the ONE barrier

    // ---- P2: S^T = mfma(K,Q); +bias; in-register softmax  (R9-proven)
    f32x4 st[9];
#pragma unroll
    for (int i = 0; i < 9; ++i) {
        bf16x8 aF = *(bf16x8*)&Ks[(i * 16 + lr) * 40 + lg * 8];
        st[i] = __builtin_amdgcn_mfma_f32_16x16x32_bf16(aF, qF, zf, 0, 0, 0);
    }
    float mx = -3.0e38f;
#pragma unroll
    for (int i = 0; i < 9; ++i)
#pragma unroll
        for (int r = 0; r < 4; ++r) {
            st[i][r] += (float)bb[i][r];
            mx = fmaxf(mx, st[i][r]);
        }
    mx = fmaxf(mx, __shfl_xor(mx, 16));
    mx = fmaxf(mx, __shfl_xor(mx, 32));
    float sum = 0.f;
#pragma unroll
    for (int i = 0; i < 9; ++i)
#pragma unroll
        for (int r = 0; r < 4; ++r) {
            float e = __expf(st[i][r] - mx);
            st[i][r] = e;
            sum += e;
        }
    sum += __shfl_xor(sum, 16);
    sum += __shfl_xor(sum, 32);
    float inv = 1.f / sum;
#pragma unroll
    for (int i = 0; i < 9; ++i)
#pragma unroll
        for (int r = 0; r < 4; ++r) st[i][r] *= inv;

    // ---- P3: O = P @ V via per-wave P scratch  (R9-proven)
    __bf16* Pw = Pws + w * 640;    // [16][40]
    f32x4 o0 = zf, o1 = zf;
#pragma unroll
    for (int s = 0; s < 4; ++s) {
#pragma unroll
        for (int d = 0; d < 2; ++d) {
            int ii = 2 * s + d;
            bf16x4 pk;
#pragma unroll
            for (int r = 0; r < 4; ++r) pk[r] = (__bf16)st[ii][r];
            *(bf16x4*)&Pw[lr * 40 + d * 16 + lg * 4] = pk;
        }
        bf16x8 aP  = *(bf16x8*)&Pw[lr * 40 + lg * 8];
        bf16x8 v0F = *(bf16x8*)&Vt[lr * 152 + s * 32 + lg * 8];
        bf16x8 v1F = *(bf16x8*)&Vt[(16 + lr) * 152 + s * 32 + lg * 8];
        o0 = __builtin_amdgcn_mfma_f32_16x16x32_bf16(aP, v0F, o0, 0, 0, 0);
        o1 = __builtin_amdgcn_mfma_f32_16x16x32_bf16(aP, v1F, o1, 0, 0, 0);
    }
    {   // tail keys 128..143: lanes lg>=2 supply zeros
        bf16x4 pk;
#pragma unroll
        for (int r = 0; r < 4; ++r) pk[r] = (__bf16)st[8][r];
        *(bf16x4*)&Pw[lr * 40 + lg * 4] = pk;
        bf16x8 aP = zb, v0F = zb, v1F = zb;
        if (lg < 2) {
            aP  = *(bf16x8*)&Pw[lr * 40 + lg * 8];
            v0F = *(bf16x8*)&Vt[lr * 152 + 128 + lg * 8];
            v1F = *(bf16x8*)&Vt[(16 + lr) * 152 + 128 + lg * 8];
        }
        o0 = __builtin_amdgcn_mfma_f32_16x16x32_bf16(aP, v0F, o0, 0, 0, 0);
        o1 = __builtin_amdgcn_mfma_f32_16x16x32_bf16(aP, v1F, o1, 0, 0, 0);
    }

    // ---- O restage (coalesce) + store to opre (h-major, aliases own q slice)
#pragma unroll
    for (int r = 0; r < 4; ++r) {
        Pw[(lg * 4 + r) * 40 + lr]      = (__bf16)o0[r];
        Pw[(lg * 4 + r) * 40 + 16 + lr] = (__bf16)o1[r];
    }
    {
        int row = lane >> 2, c = lane & 3;
        bf16x8 ov = *(bf16x8*)&Pw[row * 40 + c * 8];
        *(bf16x8*)&opre[bh * BH_STRIDE + (size_t)(m0 + row) * HD + c * 8] = ov;
    }
}

// ---------------------------------------------------------------------------
// Out-projection (R7 register-B design, h-major gather): block = one b,
// 9 M-tiles, dbuf LDS staging, W2 in registers, LDS-only barriers.
// ---------------------------------------------------------------------------
__global__ __launch_bounds__(256, 3) void k_proj(
        const char* __restrict__ ws, const float* __restrict__ b2,
        float* __restrict__ out) {
    const __bf16* opre = (const __bf16*)(ws + WS_QF);
    const __bf16* w2t  = (const __bf16*)(ws + WS_W2T);
    __shared__ __bf16 As[2][16 * 200];

    const int tid = threadIdx.x;
    const int w = tid >> 6, lr = tid & 15, lg = (tid & 63) >> 4;
    const int b = blockIdx.x;
    const f32x4 zf = {0.f, 0.f, 0.f, 0.f};

    bf16x8 bW[3][6];
    float bcol[3];
#pragma unroll
    for (int i = 0; i < 3; ++i) {
        int col = (w * 3 + i) * 16 + lr;
        bcol[i] = b2[col];
#pragma unroll
        for (int kk = 0; kk < 6; ++kk)
            bW[i][kk] = *(const bf16x8*)(w2t + (col * 192 + kk * 32 + lg * 8));
    }

    // per tile: 16 rows x 24 col-chunks (16B) = 384 chunks, h-major gather
    auto src_of = [&](int t, int c) -> const __bf16* {
        int lrow = c / 24, c8 = c % 24;
        int h = c8 >> 2, col32 = (c8 & 3) * 8;
        return opre + ((size_t)(b * NH + h)) * BH_STRIDE
                    + (size_t)(t * 16 + lrow) * HD + col32;
    };
    auto dst_of = [&](int buf, int c) -> __bf16* {
        int lrow = c / 24, c8 = c % 24;
        return &As[buf][lrow * 200 + c8 * 8];
    };

    {
        *(bf16x8*)dst_of(0, tid) = *(const bf16x8*)src_of(0, tid);
        if (tid < 128)
            *(bf16x8*)dst_of(0, tid + 256) = *(const bf16x8*)src_of(0, tid + 256);
    }

    for (int t = 0; t < 9; ++t) {
        bf16x8 n0, n1;
        if (t < 8) {
            n0 = *(const bf16x8*)src_of(t + 1, tid);
            if (tid < 128) n1 = *(const bf16x8*)src_of(t + 1, tid + 256);
        }
        lds_barrier();
        const __bf16* A = As[t & 1];
        f32x4 acc[3];
#pragma unroll
        for (int i = 0; i < 3; ++i) acc[i] = zf;
#pragma unroll
        for (int kk = 0; kk < 6; ++kk) {
            bf16x8 aF = *(const bf16x8*)&A[lr * 200 + kk * 32 + lg * 8];
#pragma unroll
            for (int i = 0; i < 3; ++i)
                acc[i] = __builtin_amdgcn_mfma_f32_16x16x32_bf16(aF, bW[i][kk], acc[i], 0, 0, 0);
        }
        size_t row0 = (size_t)b * SEQ + t * 16;
#pragma unroll
        for (int i = 0; i < 3; ++i) {
            int col = (w * 3 + i) * 16 + lr;
#pragma unroll
            for (int r = 0; r < 4; ++r)
                out[(row0 + lg * 4 + r) * DIM + col] = acc[i][r] + bcol[i];
        }
        if (t < 8) {
            *(bf16x8*)dst_of((t + 1) & 1, tid) = n0;
            if (tid < 128) *(bf16x8*)dst_of((t + 1) & 1, tid + 256) = n1;
        }
    }
}

// ---------------------------------------------------------------------------
extern "C" void kernel_launch(void* const* d_in, const int* in_sizes, int n_in,
                              void* d_out, int out_size, void* d_ws, size_t ws_size,
                              hipStream_t stream) {
    const float* x    = (const float*)d_in[0];
    const float* w1   = (const float*)d_in[1];
    const float* b1   = (const float*)d_in[2];
    const float* w2   = (const float*)d_in[3];
    const float* b2   = (const float*)d_in[4];
    const float* bt   = (const float*)d_in[5];
    const int*   pidx = (const int*)d_in[6];
    const int*   mask = (const int*)d_in[7];
    float* out = (float*)d_out;
    char*  ws  = (char*)d_ws;

    k_prep<<<658, 256, 0, stream>>>(w1, w2, b1, bt, pidx, mask, ws);
    k_qkv<<<dim3(1024, 3), 256, 0, stream>>>(x, ws);
    k_attn3<<<BATCH * NH, 576, 0, stream>>>(ws);
    k_proj<<<BATCH, 256, 0, stream>>>(ws, b2, out);
}

// Round 13
// 205.426 us; speedup vs baseline: 1.6329x; 1.0369x over previous
//
#include <hip/hip_runtime.h>

#define BATCH 1024
#define SEQ   144
#define DIM   192
#define NH    6
#define HD    32
#define SCALE 0.17677669529663687f   // 1/sqrt(32)

typedef __bf16 bf16x8 __attribute__((ext_vector_type(8)));
typedef __bf16 bf16x4 __attribute__((ext_vector_type(4)));
typedef float  f32x4  __attribute__((ext_vector_type(4)));

// LDS-only barrier (proven R9): orders ds_write->ds_read without draining vmcnt.
__device__ __forceinline__ void lds_barrier() {
    __builtin_amdgcn_sched_barrier(0);
    asm volatile("s_waitcnt lgkmcnt(0)" ::: "memory");
    __builtin_amdgcn_s_barrier();
    __builtin_amdgcn_sched_barrier(0);
}

// ---- workspace layout (bytes) ----
#define WS_W1T   0          // bf16 [576][192]  w1t[c][k] = w1[k][c] (*SCALE for c<192)
#define WS_W2T   221184     // bf16 [192][192]  w2t[n][k] = w2[k][n]
#define WS_B1S   294912     // f32  [576]       b1 (*SCALE for c<192)
#define WS_BM    297216     // bf16 [6][144][144]  bm[h][query][key] = bias + mask
#define WS_QF    546048     // bf16 [1024*6][144][32]  q ; aliased as opre after read
#define WS_KF    57169152   // bf16 [1024*6][144][32]  k
#define WS_VT    113792256  // bf16 [1024*6][32][144]  v^T
// total need 170415360 B (confirmed available in round 6)

#define BH_STRIDE 4608      // 144*32 elems per (b,h)

// ---------------------------------------------------------------------------
__global__ __launch_bounds__(256) void k_prep(
        const float* __restrict__ w1, const float* __restrict__ w2,
        const float* __restrict__ b1, const float* __restrict__ bt,
        const int* __restrict__ pidx, const int* __restrict__ mask,
        char* __restrict__ ws) {
    __bf16* w1t = (__bf16*)(ws + WS_W1T);
    __bf16* w2t = (__bf16*)(ws + WS_W2T);
    float*  b1s = (float*)(ws + WS_B1S);
    __bf16* bm  = (__bf16*)(ws + WS_BM);
    const int blk = blockIdx.x, t = threadIdx.x;
    if (blk < 432) {
        int idx = blk * 256 + t;
        int k = idx / 576, c = idx % 576;
        float v = w1[idx] * (c < 192 ? SCALE : 1.0f);
        w1t[c * 192 + k] = (__bf16)v;
    } else if (blk < 576) {
        int idx = (blk - 432) * 256 + t;
        int k = idx / 192, n = idx % 192;
        w2t[n * 192 + k] = (__bf16)w2[idx];
    } else if (blk < 657) {
        int idx = (blk - 576) * 256 + t;   // idx = query*144 + key
        int p = pidx[idx];
        float add = (mask[idx] == 0) ? -1e9f : 0.0f;
#pragma unroll
        for (int h = 0; h < NH; ++h)
            bm[h * 20736 + idx] = (__bf16)(bt[p * NH + h] + add);
    } else {
        for (int c = t; c < 576; c += 256)
            b1s[c] = b1[c] * (c < 192 ? SCALE : 1.0f);
    }
}

// ---------------------------------------------------------------------------
// QKV GEMM (proven register-B pattern). Grid 3072, XCD-swizzled so the THREE
// cg-blocks of one b land on the SAME XCD 8 dispatch-slots apart -> X is read
// from HBM once per trio, L2-hit for the other two. 4 waves; wave holds its
// 48-col W1 slice in 18 persistent B-frags. 9 M-tiles, dbuf LDS A-staging.
// ---------------------------------------------------------------------------
__global__ __launch_bounds__(256, 3) void k_qkv(
        const float* __restrict__ x, char* __restrict__ ws) {
    const __bf16* w1t = (const __bf16*)(ws + WS_W1T);
    const float*  b1s = (const float*)(ws + WS_B1S);
    __bf16* qf  = (__bf16*)(ws + WS_QF);
    __bf16* kf  = (__bf16*)(ws + WS_KF);
    __bf16* vtf = (__bf16*)(ws + WS_VT);

    __shared__ __bf16 As[2][16 * 200];
    const int tid = threadIdx.x;
    const int w = tid >> 6, lr = tid & 15, lg = (tid & 63) >> 4;

    // XCD co-location: phys -> (xcd, slot); each XCD owns 128 consecutive b's;
    // trio (b, cg=0..2) occupies slots 3k..3k+2 on ONE xcd.
    const int phys = blockIdx.x;             // 3072 = 8 xcd * 384 slots
    const int logical = (phys & 7) * 384 + (phys >> 3);
    const int b  = logical / 3;
    const int cg = logical % 3;              // 0=q, 1=k, 2=v
    const f32x4 zf = {0.f, 0.f, 0.f, 0.f};

    // persistent B-frags + bias for this wave's 48 cols of this group
    bf16x8 bW[3][6];
    float bcol[3];
#pragma unroll
    for (int i = 0; i < 3; ++i) {
        int col = cg * 192 + (w * 3 + i) * 16 + lr;
        bcol[i] = b1s[col];
#pragma unroll
        for (int kk = 0; kk < 6; ++kk)
            bW[i][kk] = *(const bf16x8*)(w1t + (col * 192 + kk * 32 + lg * 8));
    }

    // A staging: 16 rows x 192 cols fp32 = 768 f32x4 chunks, 3 per thread
    const int c0 = tid;
    auto stage = [&](int t, int buf) {
        const float* src = x + ((size_t)b * SEQ + t * 16) * DIM;
#pragma unroll
        for (int j = 0; j < 3; ++j) {
            int c = c0 + j * 256;
            int row = c / 48, c4 = (c % 48) * 4;
            f32x4 v = *(const f32x4*)&src[row * DIM + c4];
            bf16x4 pk;
            pk[0] = (__bf16)v[0]; pk[1] = (__bf16)v[1];
            pk[2] = (__bf16)v[2]; pk[3] = (__bf16)v[3];
            *(bf16x4*)&As[buf][row * 200 + c4] = pk;
        }
    };

    stage(0, 0);

    for (int t = 0; t < 9; ++t) {
        // prefetch next tile into regs
        f32x4 nxt[3];
        if (t < 8) {
            const float* src = x + ((size_t)b * SEQ + (t + 1) * 16) * DIM;
#pragma unroll
            for (int j = 0; j < 3; ++j) {
                int c = c0 + j * 256;
                int row = c / 48, c4 = (c % 48) * 4;
                nxt[j] = *(const f32x4*)&src[row * DIM + c4];
            }
        }
        lds_barrier();
        const __bf16* A = As[t & 1];
        f32x4 acc[3];
#pragma unroll
        for (int i = 0; i < 3; ++i) acc[i] = zf;
#pragma unroll
        for (int kk = 0; kk < 6; ++kk) {
            bf16x8 aF = *(const bf16x8*)&A[lr * 200 + kk * 32 + lg * 8];
#pragma unroll
            for (int i = 0; i < 3; ++i)
                acc[i] = __builtin_amdgcn_mfma_f32_16x16x32_bf16(aF, bW[i][kk], acc[i], 0, 0, 0);
        }
        // epilogue: +bias, scatter
        const int m = t * 16 + lg * 4;       // +r
#pragma unroll
        for (int i = 0; i < 3; ++i) {
            int j2 = (w * 3 + i) * 16 + lr;  // 0..191 within group
            int h = j2 >> 5, j = j2 & 31;
            size_t bh = (size_t)(b * NH + h);
            if (cg == 0) {
                __bf16* d = qf + bh * BH_STRIDE + (size_t)m * HD + j;
#pragma unroll
                for (int r = 0; r < 4; ++r) d[r * HD] = (__bf16)(acc[i][r] + bcol[i]);
            } else if (cg == 1) {
                __bf16* d = kf + bh * BH_STRIDE + (size_t)m * HD + j;
#pragma unroll
                for (int r = 0; r < 4; ++r) d[r * HD] = (__bf16)(acc[i][r] + bcol[i]);
            } else {
                bf16x4 pk;
#pragma unroll
                for (int r = 0; r < 4; ++r) pk[r] = (__bf16)(acc[i][r] + bcol[i]);
                *(bf16x4*)&vtf[bh * BH_STRIDE + (size_t)j * SEQ + m] = pk;
            }
        }
        if (t < 8) {
#pragma unroll
            for (int j = 0; j < 3; ++j) {
                int c = c0 + j * 256;
                int row = c / 48, c4 = (c % 48) * 4;
                f32x4 v = nxt[j];
                bf16x4 pk;
                pk[0] = (__bf16)v[0]; pk[1] = (__bf16)v[1];
                pk[2] = (__bf16)v[2]; pk[3] = (__bf16)v[3];
                *(bf16x4*)&As[(t + 1) & 1][row * 200 + c4] = pk;
            }
        }
    }
}

// ---------------------------------------------------------------------------
// Attention-only per (b,h) (R12-proven): K,V cooperatively staged, Q per-lane
// direct, bias L2, ONE barrier, R9 P2/softmax/P3. LDS 32768 B.
// ---------------------------------------------------------------------------
__global__ __launch_bounds__(576, 2) void k_attn3(char* __restrict__ ws) {
    const __bf16* bmB = (const __bf16*)(ws + WS_BM);
    const __bf16* qf  = (const __bf16*)(ws + WS_QF);
    const __bf16* kf  = (const __bf16*)(ws + WS_KF);
    const __bf16* vtf = (const __bf16*)(ws + WS_VT);
    __bf16* opre = (__bf16*)(ws + WS_QF);   // alias: own slice, read-then-write

    __shared__ char smem[32768];
    __bf16* Ks  = (__bf16*)smem;             // [144][40]  11520 B
    __bf16* Vt  = (__bf16*)(smem + 11520);   // [32][152]   9728 B
    __bf16* Pws = (__bf16*)(smem + 21248);   // 9 x [16][40] wave-private

    const int bx = blockIdx.x;               // 6144 = 6 h-groups x 1024 b
    const int h  = bx >> 10;
    const int b  = bx & 1023;
    const size_t bh = (size_t)(b * NH + h);

    const int tid  = threadIdx.x;
    const int w    = tid >> 6;
    const int lane = tid & 63;
    const int lr   = lane & 15;
    const int lg   = lane >> 4;
    const int m0   = w * 16;
    const f32x4 zf = {0.f, 0.f, 0.f, 0.f};
    const bf16x8 zb = {(__bf16)0.f,(__bf16)0.f,(__bf16)0.f,(__bf16)0.f,
                       (__bf16)0.f,(__bf16)0.f,(__bf16)0.f,(__bf16)0.f};

    // ---- issue all global loads up front
    bf16x8 kch = *(const bf16x8*)(kf  + bh * BH_STRIDE + (size_t)tid * 8);
    bf16x8 vch = *(const bf16x8*)(vtf + bh * BH_STRIDE + (size_t)tid * 8);
    bf16x8 qF  = *(const bf16x8*)(qf  + bh * BH_STRIDE + (size_t)(m0 + lr) * HD + lg * 8);
    bf16x4 bb[9];
    {
        const __bf16* bmh = bmB + h * 20736 + (m0 + lr) * SEQ;
#pragma unroll
        for (int i = 0; i < 9; ++i) bb[i] = *(const bf16x4*)&bmh[i * 16 + lg * 4];
    }

    // ---- stage to LDS
    *(bf16x8*)&Ks[(tid >> 2) * 40 + (tid & 3) * 8] = kch;
    {
        int vr = tid / 18, vc = tid % 18;
        *(bf16x8*)&Vt[vr * 152 + vc * 8] = vch;
    }
    lds_barrier();   // the ONE barrier

    // ---- P2: S^T = mfma(K,Q); +bias; in-register softmax
    f32x4 st[9];
#pragma unroll
    for (int i = 0; i < 9; ++i) {
        bf16x8 aF = *(bf16x8*)&Ks[(i * 16 + lr) * 40 + lg * 8];
        st[i] = __builtin_amdgcn_mfma_f32_16x16x32_bf16(aF, qF, zf, 0, 0, 0);
    }
    float mx = -3.0e38f;
#pragma unroll
    for (int i = 0; i < 9; ++i)
#pragma unroll
        for (int r = 0; r < 4; ++r) {
            st[i][r] += (float)bb[i][r];
            mx = fmaxf(mx, st[i][r]);
        }
    mx = fmaxf(mx, __shfl_xor(mx, 16));
    mx = fmaxf(mx, __shfl_xor(mx, 32));
    float sum = 0.f;
#pragma unroll
    for (int i = 0; i < 9; ++i)
#pragma unroll
        for (int r = 0; r < 4; ++r) {
            float e = __expf(st[i][r] - mx);
            st[i][r] = e;
            sum += e;
        }
    sum += __shfl_xor(sum, 16);
    sum += __shfl_xor(sum, 32);
    float inv = 1.f / sum;
#pragma unroll
    for (int i = 0; i < 9; ++i)
#pragma unroll
        for (int r = 0; r < 4; ++r) st[i][r] *= inv;

    // ---- P3: O = P @ V via per-wave P scratch
    __bf16* Pw = Pws + w * 640;    // [16][40]
    f32x4 o0 = zf, o1 = zf;
#pragma unroll
    for (int s = 0; s < 4; ++s) {
#pragma unroll
        for (int d = 0; d < 2; ++d) {
            int ii = 2 * s + d;
            bf16x4 pk;
#pragma unroll
            for (int r = 0; r < 4; ++r) pk[r] = (__bf16)st[ii][r];
            *(bf16x4*)&Pw[lr * 40 + d * 16 + lg * 4] = pk;
        }
        bf16x8 aP  = *(bf16x8*)&Pw[lr * 40 + lg * 8];
        bf16x8 v0F = *(bf16x8*)&Vt[lr * 152 + s * 32 + lg * 8];
        bf16x8 v1F = *(bf16x8*)&Vt[(16 + lr) * 152 + s * 32 + lg * 8];
        o0 = __builtin_amdgcn_mfma_f32_16x16x32_bf16(aP, v0F, o0, 0, 0, 0);
        o1 = __builtin_amdgcn_mfma_f32_16x16x32_bf16(aP, v1F, o1, 0, 0, 0);
    }
    {   // tail keys 128..143: lanes lg>=2 supply zeros
        bf16x4 pk;
#pragma unroll
        for (int r = 0; r < 4; ++r) pk[r] = (__bf16)st[8][r];
        *(bf16x4*)&Pw[lr * 40 + lg * 4] = pk;
        bf16x8 aP = zb, v0F = zb, v1F = zb;
        if (lg < 2) {
            aP  = *(bf16x8*)&Pw[lr * 40 + lg * 8];
            v0F = *(bf16x8*)&Vt[lr * 152 + 128 + lg * 8];
            v1F = *(bf16x8*)&Vt[(16 + lr) * 152 + 128 + lg * 8];
        }
        o0 = __builtin_amdgcn_mfma_f32_16x16x32_bf16(aP, v0F, o0, 0, 0, 0);
        o1 = __builtin_amdgcn_mfma_f32_16x16x32_bf16(aP, v1F, o1, 0, 0, 0);
    }

    // ---- O restage (coalesce) + store to opre (h-major, aliases own q slice)
#pragma unroll
    for (int r = 0; r < 4; ++r) {
        Pw[(lg * 4 + r) * 40 + lr]      = (__bf16)o0[r];
        Pw[(lg * 4 + r) * 40 + 16 + lr] = (__bf16)o1[r];
    }
    {
        int row = lane >> 2, c = lane & 3;
        bf16x8 ov = *(bf16x8*)&Pw[row * 40 + c * 8];
        *(bf16x8*)&opre[bh * BH_STRIDE + (size_t)(m0 + row) * HD + c * 8] = ov;
    }
}

// ---------------------------------------------------------------------------
// Out-projection (R12-proven): register-B, h-major gather, dbuf staging.
// ---------------------------------------------------------------------------
__global__ __launch_bounds__(256, 3) void k_proj(
        const char* __restrict__ ws, const float* __restrict__ b2,
        float* __restrict__ out) {
    const __bf16* opre = (const __bf16*)(ws + WS_QF);
    const __bf16* w2t  = (const __bf16*)(ws + WS_W2T);
    __shared__ __bf16 As[2][16 * 200];

    const int tid = threadIdx.x;
    const int w = tid >> 6, lr = tid & 15, lg = (tid & 63) >> 4;
    const int b = blockIdx.x;
    const f32x4 zf = {0.f, 0.f, 0.f, 0.f};

    bf16x8 bW[3][6];
    float bcol[3];
#pragma unroll
    for (int i = 0; i < 3; ++i) {
        int col = (w * 3 + i) * 16 + lr;
        bcol[i] = b2[col];
#pragma unroll
        for (int kk = 0; kk < 6; ++kk)
            bW[i][kk] = *(const bf16x8*)(w2t + (col * 192 + kk * 32 + lg * 8));
    }

    auto src_of = [&](int t, int c) -> const __bf16* {
        int lrow = c / 24, c8 = c % 24;
        int h = c8 >> 2, col32 = (c8 & 3) * 8;
        return opre + ((size_t)(b * NH + h)) * BH_STRIDE
                    + (size_t)(t * 16 + lrow) * HD + col32;
    };
    auto dst_of = [&](int buf, int c) -> __bf16* {
        int lrow = c / 24, c8 = c % 24;
        return &As[buf][lrow * 200 + c8 * 8];
    };

    {
        *(bf16x8*)dst_of(0, tid) = *(const bf16x8*)src_of(0, tid);
        if (tid < 128)
            *(bf16x8*)dst_of(0, tid + 256) = *(const bf16x8*)src_of(0, tid + 256);
    }

    for (int t = 0; t < 9; ++t) {
        bf16x8 n0, n1;
        if (t < 8) {
            n0 = *(const bf16x8*)src_of(t + 1, tid);
            if (tid < 128) n1 = *(const bf16x8*)src_of(t + 1, tid + 256);
        }
        lds_barrier();
        const __bf16* A = As[t & 1];
        f32x4 acc[3];
#pragma unroll
        for (int i = 0; i < 3; ++i) acc[i] = zf;
#pragma unroll
        for (int kk = 0; kk < 6; ++kk) {
            bf16x8 aF = *(const bf16x8*)&A[lr * 200 + kk * 32 + lg * 8];
#pragma unroll
            for (int i = 0; i < 3; ++i)
                acc[i] = __builtin_amdgcn_mfma_f32_16x16x32_bf16(aF, bW[i][kk], acc[i], 0, 0, 0);
        }
        size_t row0 = (size_t)b * SEQ + t * 16;
#pragma unroll
        for (int i = 0; i < 3; ++i) {
            int col = (w * 3 + i) * 16 + lr;
#pragma unroll
            for (int r = 0; r < 4; ++r)
                out[(row0 + lg * 4 + r) * DIM + col] = acc[i][r] + bcol[i];
        }
        if (t < 8) {
            *(bf16x8*)dst_of((t + 1) & 1, tid) = n0;
            if (tid < 128) *(bf16x8*)dst_of((t + 1) & 1, tid + 256) = n1;
        }
    }
}

// ---------------------------------------------------------------------------
extern "C" void kernel_launch(void* const* d_in, const int* in_sizes, int n_in,
                              void* d_out, int out_size, void* d_ws, size_t ws_size,
                              hipStream_t stream) {
    const float* x    = (const float*)d_in[0];
    const float* w1   = (const float*)d_in[1];
    const float* b1   = (const float*)d_in[2];
    const float* w2   = (const float*)d_in[3];
    const float* b2   = (const float*)d_in[4];
    const float* bt   = (const float*)d_in[5];
    const int*   pidx = (const int*)d_in[6];
    const int*   mask = (const int*)d_in[7];
    float* out = (float*)d_out;
    char*  ws  = (char*)d_ws;

    k_prep<<<658, 256, 0, stream>>>(w1, w2, b1, bt, pidx, mask, ws);
    k_qkv<<<3072, 256, 0, stream>>>(x, ws);
    k_attn3<<<BATCH * NH, 576, 0, stream>>>(ws);
    k_proj<<<BATCH, 256, 0, stream>>>(ws, b2, out);
}

// Round 14
// 190.834 us; speedup vs baseline: 1.7577x; 1.0765x over previous
//
#include <hip/hip_runtime.h>

#define BATCH 1024
#define SEQ   144
#define DIM   192
#define NH    6
#define HD    32
#define SCALE 0.17677669529663687f   // 1/sqrt(32)

typedef __bf16 bf16x8 __attribute__((ext_vector_type(8)));
typedef __bf16 bf16x4 __attribute__((ext_vector_type(4)));
typedef float  f32x4  __attribute__((ext_vector_type(4)));

// LDS-only barrier (proven R9): orders ds_write->ds_read without draining vmcnt.
__device__ __forceinline__ void lds_barrier() {
    __builtin_amdgcn_sched_barrier(0);
    asm volatile("s_waitcnt lgkmcnt(0)" ::: "memory");
    __builtin_amdgcn_s_barrier();
    __builtin_amdgcn_sched_barrier(0);
}

// ---- workspace layout (bytes) ----
#define WS_W1T   0          // bf16 [576][192]  w1t[c][k] = w1[k][c] (*SCALE for c<192)
#define WS_W2T   221184     // bf16 [192][192]  w2t[n][k] = w2[k][n]
#define WS_B1S   294912     // f32  [576]       b1 (*SCALE for c<192)
#define WS_BM    297216     // bf16 [6][144][144]  bm[h][query][key] = bias + mask
#define WS_QF    546048     // bf16 [1024*6][144][32]  q ; aliased as opre after read
#define WS_KF    57169152   // bf16 [1024*6][144][32]  k
#define WS_VT    113792256  // bf16 [1024*6][32][144]  v^T
// total need 170415360 B (confirmed available in round 6)

#define BH_STRIDE 4608      // 144*32 elems per (b,h)

// ---------------------------------------------------------------------------
__global__ __launch_bounds__(256) void k_prep(
        const float* __restrict__ w1, const float* __restrict__ w2,
        const float* __restrict__ b1, const float* __restrict__ bt,
        const int* __restrict__ pidx, const int* __restrict__ mask,
        char* __restrict__ ws) {
    __bf16* w1t = (__bf16*)(ws + WS_W1T);
    __bf16* w2t = (__bf16*)(ws + WS_W2T);
    float*  b1s = (float*)(ws + WS_B1S);
    __bf16* bm  = (__bf16*)(ws + WS_BM);
    const int blk = blockIdx.x, t = threadIdx.x;
    if (blk < 432) {
        int idx = blk * 256 + t;
        int k = idx / 576, c = idx % 576;
        float v = w1[idx] * (c < 192 ? SCALE : 1.0f);
        w1t[c * 192 + k] = (__bf16)v;
    } else if (blk < 576) {
        int idx = (blk - 432) * 256 + t;
        int k = idx / 192, n = idx % 192;
        w2t[n * 192 + k] = (__bf16)w2[idx];
    } else if (blk < 657) {
        int idx = (blk - 576) * 256 + t;   // idx = query*144 + key
        int p = pidx[idx];
        float add = (mask[idx] == 0) ? -1e9f : 0.0f;
#pragma unroll
        for (int h = 0; h < NH; ++h)
            bm[h * 20736 + idx] = (__bf16)(bt[p * NH + h] + add);
    } else {
        for (int c = t; c < 576; c += 256)
            b1s[c] = b1[c] * (c < 192 ? SCALE : 1.0f);
    }
}

// ---------------------------------------------------------------------------
// QKV GEMM (register-B pattern + XCD trio co-location, R13-proven on FETCH).
// NEW: q/k epilogue restaged through wave-private LDS -> bf16x8 coalesced
// stores (12 short-stores/thread/tile -> 1.5 dwordx4). V path unchanged.
// ---------------------------------------------------------------------------
__global__ __launch_bounds__(256, 3) void k_qkv(
        const float* __restrict__ x, char* __restrict__ ws) {
    const __bf16* w1t = (const __bf16*)(ws + WS_W1T);
    const float*  b1s = (const float*)(ws + WS_B1S);
    __bf16* qf  = (__bf16*)(ws + WS_QF);
    __bf16* kf  = (__bf16*)(ws + WS_KF);
    __bf16* vtf = (__bf16*)(ws + WS_VT);

    __shared__ __bf16 As[2][16 * 200];      // 12800 B
    __shared__ __bf16 Stg[4][16 * 56];      // 7168 B: per-wave q/k restage

    const int tid = threadIdx.x;
    const int w = tid >> 6, lane = tid & 63, lr = tid & 15, lg = (tid & 63) >> 4;

    // XCD co-location: trio (b, cg=0..2) on one XCD 8 slots apart.
    const int phys = blockIdx.x;             // 3072 = 8 xcd * 384 slots
    const int logical = (phys & 7) * 384 + (phys >> 3);
    const int b  = logical / 3;
    const int cg = logical % 3;              // 0=q, 1=k, 2=v
    const f32x4 zf = {0.f, 0.f, 0.f, 0.f};

    // persistent B-frags + bias for this wave's 48 cols of this group
    bf16x8 bW[3][6];
    float bcol[3];
#pragma unroll
    for (int i = 0; i < 3; ++i) {
        int col = cg * 192 + (w * 3 + i) * 16 + lr;
        bcol[i] = b1s[col];
#pragma unroll
        for (int kk = 0; kk < 6; ++kk)
            bW[i][kk] = *(const bf16x8*)(w1t + (col * 192 + kk * 32 + lg * 8));
    }

    __bf16* qk_dst = (cg == 0) ? qf : kf;
    __bf16* stg = Stg[w];

    // A staging: 16 rows x 192 cols fp32 = 768 f32x4 chunks, 3 per thread
    const int c0 = tid;
    auto stage = [&](int t, int buf) {
        const float* src = x + ((size_t)b * SEQ + t * 16) * DIM;
#pragma unroll
        for (int j = 0; j < 3; ++j) {
            int c = c0 + j * 256;
            int row = c / 48, c4 = (c % 48) * 4;
            f32x4 v = *(const f32x4*)&src[row * DIM + c4];
            bf16x4 pk;
            pk[0] = (__bf16)v[0]; pk[1] = (__bf16)v[1];
            pk[2] = (__bf16)v[2]; pk[3] = (__bf16)v[3];
            *(bf16x4*)&As[buf][row * 200 + c4] = pk;
        }
    };

    stage(0, 0);

    for (int t = 0; t < 9; ++t) {
        // prefetch next tile into regs
        f32x4 nxt[3];
        if (t < 8) {
            const float* src = x + ((size_t)b * SEQ + (t + 1) * 16) * DIM;
#pragma unroll
            for (int j = 0; j < 3; ++j) {
                int c = c0 + j * 256;
                int row = c / 48, c4 = (c % 48) * 4;
                nxt[j] = *(const f32x4*)&src[row * DIM + c4];
            }
        }
        lds_barrier();
        const __bf16* A = As[t & 1];
        f32x4 acc[3];
#pragma unroll
        for (int i = 0; i < 3; ++i) acc[i] = zf;
#pragma unroll
        for (int kk = 0; kk < 6; ++kk) {
            bf16x8 aF = *(const bf16x8*)&A[lr * 200 + kk * 32 + lg * 8];
#pragma unroll
            for (int i = 0; i < 3; ++i)
                acc[i] = __builtin_amdgcn_mfma_f32_16x16x32_bf16(aF, bW[i][kk], acc[i], 0, 0, 0);
        }

        // ---- epilogue
        if (cg < 2) {
            // restage to wave-private LDS [16 m][56] (+bias, bf16)
#pragma unroll
            for (int i = 0; i < 3; ++i)
#pragma unroll
                for (int r = 0; r < 4; ++r)
                    stg[(lg * 4 + r) * 56 + i * 16 + lr] = (__bf16)(acc[i][r] + bcol[i]);
            // wave-internal readback (compiler inserts lgkmcnt wait) + 16B stores
            // chunk c in [0,96): m=c/6, c8=c%6 ; dst j2 = w*48 + c8*8
#pragma unroll
            for (int rep = 0; rep < 2; ++rep) {
                int c = lane + rep * 64;
                if (rep == 0 || lane < 32) {
                    int m = c / 6, c8 = c % 6;
                    bf16x8 v = *(bf16x8*)&stg[m * 56 + c8 * 8];
                    int j2 = w * 48 + c8 * 8;
                    int h = j2 >> 5, j = j2 & 31;
                    size_t bh = (size_t)b * NH + h;
                    *(bf16x8*)&qk_dst[bh * BH_STRIDE + (size_t)(t * 16 + m) * HD + j] = v;
                }
            }
        } else {
            const int m = t * 16 + lg * 4;
#pragma unroll
            for (int i = 0; i < 3; ++i) {
                int j2 = (w * 3 + i) * 16 + lr;
                int h = j2 >> 5, j = j2 & 31;
                size_t bh = (size_t)b * NH + h;
                bf16x4 pk;
#pragma unroll
                for (int r = 0; r < 4; ++r) pk[r] = (__bf16)(acc[i][r] + bcol[i]);
                *(bf16x4*)&vtf[bh * BH_STRIDE + (size_t)j * SEQ + m] = pk;
            }
        }

        if (t < 8) {
#pragma unroll
            for (int j = 0; j < 3; ++j) {
                int c = c0 + j * 256;
                int row = c / 48, c4 = (c % 48) * 4;
                f32x4 v = nxt[j];
                bf16x4 pk;
                pk[0] = (__bf16)v[0]; pk[1] = (__bf16)v[1];
                pk[2] = (__bf16)v[2]; pk[3] = (__bf16)v[3];
                *(bf16x4*)&As[(t + 1) & 1][row * 200 + c4] = pk;
            }
        }
    }
}

// ---------------------------------------------------------------------------
// Attention-only per (b,h) (R12-proven): K,V cooperatively staged, Q per-lane
// direct, bias L2, ONE barrier, R9 P2/softmax/P3. LDS 32768 B.
// ---------------------------------------------------------------------------
__global__ __launch_bounds__(576, 2) void k_attn3(char* __restrict__ ws) {
    const __bf16* bmB = (const __bf16*)(ws + WS_BM);
    const __bf16* qf  = (const __bf16*)(ws + WS_QF);
    const __bf16* kf  = (const __bf16*)(ws + WS_KF);
    const __bf16* vtf = (const __bf16*)(ws + WS_VT);
    __bf16* opre = (__bf16*)(ws + WS_QF);   // alias: own slice, read-then-write

    __shared__ char smem[32768];
    __bf16* Ks  = (__bf16*)smem;             // [144][40]  11520 B
    __bf16* Vt  = (__bf16*)(smem + 11520);   // [32][152]   9728 B
    __bf16* Pws = (__bf16*)(smem + 21248);   // 9 x [16][40] wave-private

    const int bx = blockIdx.x;               // 6144 = 6 h-groups x 1024 b
    const int h  = bx >> 10;
    const int b  = bx & 1023;
    const size_t bh = (size_t)(b * NH + h);

    const int tid  = threadIdx.x;
    const int w    = tid >> 6;
    const int lane = tid & 63;
    const int lr   = lane & 15;
    const int lg   = lane >> 4;
    const int m0   = w * 16;
    const f32x4 zf = {0.f, 0.f, 0.f, 0.f};
    const bf16x8 zb = {(__bf16)0.f,(__bf16)0.f,(__bf16)0.f,(__bf16)0.f,
                       (__bf16)0.f,(__bf16)0.f,(__bf16)0.f,(__bf16)0.f};

    // ---- issue all global loads up front
    bf16x8 kch = *(const bf16x8*)(kf  + bh * BH_STRIDE + (size_t)tid * 8);
    bf16x8 vch = *(const bf16x8*)(vtf + bh * BH_STRIDE + (size_t)tid * 8);
    bf16x8 qF  = *(const bf16x8*)(qf  + bh * BH_STRIDE + (size_t)(m0 + lr) * HD + lg * 8);
    bf16x4 bb[9];
    {
        const __bf16* bmh = bmB + h * 20736 + (m0 + lr) * SEQ;
#pragma unroll
        for (int i = 0; i < 9; ++i) bb[i] = *(const bf16x4*)&bmh[i * 16 + lg * 4];
    }

    // ---- stage to LDS
    *(bf16x8*)&Ks[(tid >> 2) * 40 + (tid & 3) * 8] = kch;
    {
        int vr = tid / 18, vc = tid % 18;
        *(bf16x8*)&Vt[vr * 152 + vc * 8] = vch;
    }
    lds_barrier();   // the ONE barrier

    // ---- P2: S^T = mfma(K,Q); +bias; in-register softmax
    f32x4 st[9];
#pragma unroll
    for (int i = 0; i < 9; ++i) {
        bf16x8 aF = *(bf16x8*)&Ks[(i * 16 + lr) * 40 + lg * 8];
        st[i] = __builtin_amdgcn_mfma_f32_16x16x32_bf16(aF, qF, zf, 0, 0, 0);
    }
    float mx = -3.0e38f;
#pragma unroll
    for (int i = 0; i < 9; ++i)
#pragma unroll
        for (int r = 0; r < 4; ++r) {
            st[i][r] += (float)bb[i][r];
            mx = fmaxf(mx, st[i][r]);
        }
    mx = fmaxf(mx, __shfl_xor(mx, 16));
    mx = fmaxf(mx, __shfl_xor(mx, 32));
    float sum = 0.f;
#pragma unroll
    for (int i = 0; i < 9; ++i)
#pragma unroll
        for (int r = 0; r < 4; ++r) {
            float e = __expf(st[i][r] - mx);
            st[i][r] = e;
            sum += e;
        }
    sum += __shfl_xor(sum, 16);
    sum += __shfl_xor(sum, 32);
    float inv = 1.f / sum;
#pragma unroll
    for (int i = 0; i < 9; ++i)
#pragma unroll
        for (int r = 0; r < 4; ++r) st[i][r] *= inv;

    // ---- P3: O = P @ V via per-wave P scratch
    __bf16* Pw = Pws + w * 640;    // [16][40]
    f32x4 o0 = zf, o1 = zf;
#pragma unroll
    for (int s = 0; s < 4; ++s) {
#pragma unroll
        for (int d = 0; d < 2; ++d) {
            int ii = 2 * s + d;
            bf16x4 pk;
#pragma unroll
            for (int r = 0; r < 4; ++r) pk[r] = (__bf16)st[ii][r];
            *(bf16x4*)&Pw[lr * 40 + d * 16 + lg * 4] = pk;
        }
        bf16x8 aP  = *(bf16x8*)&Pw[lr * 40 + lg * 8];
        bf16x8 v0F = *(bf16x8*)&Vt[lr * 152 + s * 32 + lg * 8];
        bf16x8 v1F = *(bf16x8*)&Vt[(16 + lr) * 152 + s * 32 + lg * 8];
        o0 = __builtin_amdgcn_mfma_f32_16x16x32_bf16(aP, v0F, o0, 0, 0, 0);
        o1 = __builtin_amdgcn_mfma_f32_16x16x32_bf16(aP, v1F, o1, 0, 0, 0);
    }
    {   // tail keys 128..143: lanes lg>=2 supply zeros
        bf16x4 pk;
#pragma unroll
        for (int r = 0; r < 4; ++r) pk[r] = (__bf16)st[8][r];
        *(bf16x4*)&Pw[lr * 40 + lg * 4] = pk;
        bf16x8 aP = zb, v0F = zb, v1F = zb;
        if (lg < 2) {
            aP  = *(bf16x8*)&Pw[lr * 40 + lg * 8];
            v0F = *(bf16x8*)&Vt[lr * 152 + 128 + lg * 8];
            v1F = *(bf16x8*)&Vt[(16 + lr) * 152 + 128 + lg * 8];
        }
        o0 = __builtin_amdgcn_mfma_f32_16x16x32_bf16(aP, v0F, o0, 0, 0, 0);
        o1 = __builtin_amdgcn_mfma_f32_16x16x32_bf16(aP, v1F, o1, 0, 0, 0);
    }

    // ---- O restage (coalesce) + store to opre (h-major, aliases own q slice)
#pragma unroll
    for (int r = 0; r < 4; ++r) {
        Pw[(lg * 4 + r) * 40 + lr]      = (__bf16)o0[r];
        Pw[(lg * 4 + r) * 40 + 16 + lr] = (__bf16)o1[r];
    }
    {
        int row = lane >> 2, c = lane & 3;
        bf16x8 ov = *(bf16x8*)&Pw[row * 40 + c * 8];
        *(bf16x8*)&opre[bh * BH_STRIDE + (size_t)(m0 + row) * HD + c * 8] = ov;
    }
}

// ---------------------------------------------------------------------------
// Out-projection (R12-proven): register-B, h-major gather, dbuf staging.
// ---------------------------------------------------------------------------
__global__ __launch_bounds__(256, 3) void k_proj(
        const char* __restrict__ ws, const float* __restrict__ b2,
        float* __restrict__ out) {
    const __bf16* opre = (const __bf16*)(ws + WS_QF);
    const __bf16* w2t  = (const __bf16*)(ws + WS_W2T);
    __shared__ __bf16 As[2][16 * 200];

    const int tid = threadIdx.x;
    const int w = tid >> 6, lr = tid & 15, lg = (tid & 63) >> 4;
    const int b = blockIdx.x;
    const f32x4 zf = {0.f, 0.f, 0.f, 0.f};

    bf16x8 bW[3][6];
    float bcol[3];
#pragma unroll
    for (int i = 0; i < 3; ++i) {
        int col = (w * 3 + i) * 16 + lr;
        bcol[i] = b2[col];
#pragma unroll
        for (int kk = 0; kk < 6; ++kk)
            bW[i][kk] = *(const bf16x8*)(w2t + (col * 192 + kk * 32 + lg * 8));
    }

    auto src_of = [&](int t, int c) -> const __bf16* {
        int lrow = c / 24, c8 = c % 24;
        int h = c8 >> 2, col32 = (c8 & 3) * 8;
        return opre + ((size_t)(b * NH + h)) * BH_STRIDE
                    + (size_t)(t * 16 + lrow) * HD + col32;
    };
    auto dst_of = [&](int buf, int c) -> __bf16* {
        int lrow = c / 24, c8 = c % 24;
        return &As[buf][lrow * 200 + c8 * 8];
    };

    {
        *(bf16x8*)dst_of(0, tid) = *(const bf16x8*)src_of(0, tid);
        if (tid < 128)
            *(bf16x8*)dst_of(0, tid + 256) = *(const bf16x8*)src_of(0, tid + 256);
    }

    for (int t = 0; t < 9; ++t) {
        bf16x8 n0, n1;
        if (t < 8) {
            n0 = *(const bf16x8*)src_of(t + 1, tid);
            if (tid < 128) n1 = *(const bf16x8*)src_of(t + 1, tid + 256);
        }
        lds_barrier();
        const __bf16* A = As[t & 1];
        f32x4 acc[3];
#pragma unroll
        for (int i = 0; i < 3; ++i) acc[i] = zf;
#pragma unroll
        for (int kk = 0; kk < 6; ++kk) {
            bf16x8 aF = *(const bf16x8*)&A[lr * 200 + kk * 32 + lg * 8];
#pragma unroll
            for (int i = 0; i < 3; ++i)
                acc[i] = __builtin_amdgcn_mfma_f32_16x16x32_bf16(aF, bW[i][kk], acc[i], 0, 0, 0);
        }
        size_t row0 = (size_t)b * SEQ + t * 16;
#pragma unroll
        for (int i = 0; i < 3; ++i) {
            int col = (w * 3 + i) * 16 + lr;
#pragma unroll
            for (int r = 0; r < 4; ++r)
                out[(row0 + lg * 4 + r) * DIM + col] = acc[i][r] + bcol[i];
        }
        if (t < 8) {
            *(bf16x8*)dst_of((t + 1) & 1, tid) = n0;
            if (tid < 128) *(bf16x8*)dst_of((t + 1) & 1, tid + 256) = n1;
        }
    }
}

// ---------------------------------------------------------------------------
extern "C" void kernel_launch(void* const* d_in, const int* in_sizes, int n_in,
                              void* d_out, int out_size, void* d_ws, size_t ws_size,
                              hipStream_t stream) {
    const float* x    = (const float*)d_in[0];
    const float* w1   = (const float*)d_in[1];
    const float* b1   = (const float*)d_in[2];
    const float* w2   = (const float*)d_in[3];
    const float* b2   = (const float*)d_in[4];
    const float* bt   = (const float*)d_in[5];
    const int*   pidx = (const int*)d_in[6];
    const int*   mask = (const int*)d_in[7];
    float* out = (float*)d_out;
    char*  ws  = (char*)d_ws;

    k_prep<<<658, 256, 0, stream>>>(w1, w2, b1, bt, pidx, mask, ws);
    k_qkv<<<3072, 256, 0, stream>>>(x, ws);
    k_attn3<<<BATCH * NH, 576, 0, stream>>>(ws);
    k_proj<<<BATCH, 256, 0, stream>>>(ws, b2, out);
}